// Round 19
// baseline (907.667 us; speedup 1.0000x reference)
//
#include <hip/hip_runtime.h>
#include <hip/hip_bf16.h>
#include <cstdint>

// Problem constants
#define NE 16            // experts
#define D_ 2048          // d_model
#define F_ 1408          // ffn hidden
#define NTOK 8192        // B*S
#define NPAIR (NTOK * 2) // routed token-expert pairs
#define SHARED_BASE NPAIR
#define NTOT (NPAIR + NTOK) // + shared-expert rows

// ffn1: BM=256 x BN=128, BK=64, 8 waves + cvt tail (w_down/sw_down).
// ffn2: BM=256 x BN=256, BK=64, 8 waves + XCD map.
// Both use the T3 minimum-2-phase loop (m248): STAGE issued at TOP of step
// into the buffer freed by the previous barrier; ONE vmcnt(0)+barrier per
// K-step (load flight hides under ds_read+MFMA).
#define BM1 256
#define BN1 128
#define BN2 256
#define BK 64
#define NF1 (F_ / BN1)   // 11 f-tiles in ffn1
#define NF2 (D_ / BN2)   // 8 d-tiles in ffn2
#define MAXRT 111        // worst-case row-tiles: 79 routed + 32 shared
#define GEMMB1 (MAXRT * NF1) // 1221 GEMM blocks in ffn1
#define CVTB 512             // cvt tail blocks fused into ffn1
#define ROUTEB (NTOK / 4)    // 2048 routing blocks
#define CVTB2 2048           // cvt tail blocks fused into route

typedef __attribute__((ext_vector_type(8))) short short8;
typedef __attribute__((ext_vector_type(4))) float f32x4;

static __device__ __forceinline__ ushort f2bf(float f) {
    union { float f; unsigned u; } v; v.f = f;
    unsigned u = v.u;
    return (ushort)((u + 0x7FFFu + ((u >> 16) & 1u)) >> 16); // RNE
}

static __device__ __forceinline__ float bf2f(ushort u) {
    union { unsigned u; float f; } v; v.u = ((unsigned)u) << 16;
    return v.f;
}

static __device__ __forceinline__ void cvt_store8(ushort* dst, const float* src) {
    const float4* s = reinterpret_cast<const float4*>(src);
    float4 a = s[0], b = s[1];
    short8 v;
    v[0] = (short)f2bf(a.x); v[1] = (short)f2bf(a.y);
    v[2] = (short)f2bf(a.z); v[3] = (short)f2bf(a.w);
    v[4] = (short)f2bf(b.x); v[5] = (short)f2bf(b.y);
    v[6] = (short)f2bf(b.z); v[7] = (short)f2bf(b.w);
    *reinterpret_cast<short8*>(dst) = v;
}

// async global->LDS, 16B/lane; LDS dest = wave-uniform base (+lane*16 implicit)
static __device__ __forceinline__ void gll16(const void* g, void* l) {
    __builtin_amdgcn_global_load_lds((const __attribute__((address_space(1))) void*)g,
                                     (__attribute__((address_space(3))) void*)l, 16, 0, 0);
}

// T1: bijective XCD-chunking (m204). Physical block p -> XCD p%8; this gives
// each XCD a contiguous logical range so fx/dx-major neighbors (same weight
// panel) share one per-XCD L2. Proven on ffn1 (FETCH 7.0e5 -> 3.8e5 KB).
static __device__ __forceinline__ int xcd_map(int p, int nwg) {
    int q = nwg >> 3, r = nwg & 7;
    int x = p & 7, k = p >> 3;
    int base = (x < r) ? x * (q + 1) : r * (q + 1) + (x - r) * q;
    return base + k;
}

// ---------------- routing (+ fused cvt tail for ffn1's inputs) ----------------
__global__ __launch_bounds__(256) void k_route(const float* __restrict__ x,
                                               const float* __restrict__ gate_w,
                                               const float* __restrict__ expert_bias,
                                               int* __restrict__ topk_idx,
                                               float* __restrict__ topk_w,
                                               const float* __restrict__ w_gate,
                                               const float* __restrict__ w_up,
                                               const float* __restrict__ sw_gate,
                                               const float* __restrict__ sw_up,
                                               ushort* __restrict__ xb,
                                               ushort* __restrict__ wgb,
                                               ushort* __restrict__ wub,
                                               ushort* __restrict__ swgb,
                                               ushort* __restrict__ swub) {
    if (blockIdx.x >= ROUTEB) {
        // fused cvt tail: x, w_gate, w_up, sw_gate, sw_up (16B chunks, grid-stride)
        const int NX8 = NTOK * D_ / 8;
        const int NW8 = NE * F_ * D_ / 8;
        const int NSW8 = F_ * D_ / 8;
        const int TOT = NX8 + 2 * NW8 + 2 * NSW8;
        int ci = (blockIdx.x - ROUTEB) * 256 + threadIdx.x;
        const int cstride = CVTB2 * 256;
        for (; ci < TOT; ci += cstride) {
            int j = ci;
            if (j < NX8) { cvt_store8(xb + (size_t)j * 8, x + (size_t)j * 8); continue; }
            j -= NX8;
            if (j < NW8) { cvt_store8(wgb + (size_t)j * 8, w_gate + (size_t)j * 8); continue; }
            j -= NW8;
            if (j < NW8) { cvt_store8(wub + (size_t)j * 8, w_up + (size_t)j * 8); continue; }
            j -= NW8;
            if (j < NSW8) { cvt_store8(swgb + (size_t)j * 8, sw_gate + (size_t)j * 8); continue; }
            j -= NSW8;
            cvt_store8(swub + (size_t)j * 8, sw_up + (size_t)j * 8);
        }
        return;
    }

    const int wave = threadIdx.x >> 6;
    const int lane = threadIdx.x & 63;
    const int tok = blockIdx.x * 4 + wave;
    if (tok >= NTOK) return;
    const float* xr = x + (size_t)tok * D_;
    float xv[D_ / 64];
#pragma unroll
    for (int i = 0; i < D_ / 64; ++i) xv[i] = xr[lane + 64 * i];

    float logits[NE];
#pragma unroll
    for (int e = 0; e < NE; ++e) {
        const float* gw = gate_w + e * D_;
        float p = 0.f;
#pragma unroll
        for (int i = 0; i < D_ / 64; ++i) p += xv[i] * gw[lane + 64 * i];
#pragma unroll
        for (int off = 32; off > 0; off >>= 1) p += __shfl_xor(p, off, 64);
        logits[e] = p;
    }
    int i1 = 0; float b1 = logits[0] + expert_bias[0];
#pragma unroll
    for (int e = 1; e < NE; ++e) {
        float b = logits[e] + expert_bias[e];
        if (b > b1) { b1 = b; i1 = e; }
    }
    int i2 = -1; float b2 = -3.4e38f;
#pragma unroll
    for (int e = 0; e < NE; ++e) {
        if (e == i1) continue;
        float b = logits[e] + expert_bias[e];
        if (b > b2) { b2 = b; i2 = e; }
    }
    float l1 = logits[i1], l2 = logits[i2];
    float m = fmaxf(l1, l2);
    float e1 = __expf(l1 - m), e2 = __expf(l2 - m);
    float s = e1 + e2;
    if (lane == 0) {
        topk_idx[tok * 2 + 0] = i1;
        topk_idx[tok * 2 + 1] = i2;
        topk_w[tok * 2 + 0] = e1 / s;
        topk_w[tok * 2 + 1] = e2 / s;
    }
}

// ---------------- bookkeeping ----------------
// meta (ints): [0:16) cnt, [16:32) cnt2, [32:49) row prefix,
//              [64:82) block-tile prefix (16 experts, then routed total, then +shared)
__global__ void k_zero_meta(int* meta) {
    if (threadIdx.x < 128) meta[threadIdx.x] = 0;
}

__global__ __launch_bounds__(256) void k_count(const int* __restrict__ topk_idx,
                                               int* __restrict__ meta) {
    int t = blockIdx.x * 256 + threadIdx.x;
    if (t >= NTOK) return;
    atomicAdd(&meta[topk_idx[t * 2 + 0]], 1);
    atomicAdd(&meta[topk_idx[t * 2 + 1]], 1);
}

__global__ void k_prefix(int* meta) {
    if (threadIdx.x == 0) {
        int acc = 0;
        for (int e = 0; e < NE; ++e) { meta[32 + e] = acc; acc += meta[e]; }
        meta[32 + NE] = acc;
        int t = 0;
        for (int e = 0; e < NE; ++e) { meta[64 + e] = t; t += (meta[e] + BM1 - 1) / BM1; }
        meta[64 + NE] = t;                  // routed tile total == start of shared tiles
        meta[64 + NE + 1] = t + NTOK / BM1; // total incl shared
    }
}

__global__ __launch_bounds__(256) void k_scatter(const int* __restrict__ topk_idx,
                                                 const float* __restrict__ topk_w,
                                                 int* __restrict__ meta,
                                                 int* __restrict__ tok_sorted,
                                                 float* __restrict__ w_sorted,
                                                 int* __restrict__ inv) {
    int t = blockIdx.x * 256 + threadIdx.x;
    if (t >= NTOK) return;
#pragma unroll
    for (int k = 0; k < 2; ++k) {
        int e = topk_idx[t * 2 + k];
        int p = atomicAdd(&meta[16 + e], 1);
        int idx = meta[32 + e] + p;
        tok_sorted[idx] = t;
        w_sorted[idx] = topk_w[t * 2 + k];
        inv[t * 2 + k] = idx; // token -> slot map for the gather
    }
}

// expert lookup for fx-major compact grids
static __device__ __forceinline__ bool grid_decode(const int* meta, int bid, int NF,
                                                   int& e, int& row0, int& fx) {
    if (bid >= meta[64 + NE + 1] * NF) return false;
    e = (bid >= meta[64 + NE] * NF) ? NE : 0;
    if (e == 0) {
#pragma unroll
        for (int i = 1; i < NE; ++i) if (bid >= meta[64 + i] * NF) e = i;
    }
    const int tile_base = meta[64 + e];
    const int nrt = meta[64 + e + 1] - tile_base;
    const int bw = bid - tile_base * NF;
    fx = bw / nrt;
    row0 = (bw - fx * nrt) * BM1;
    return true;
}

// ---------------- pass A: h = w_route * silu(x@wg^T) * (x@wu^T) ----------------
// T3-min loop: stage(t+1) issued at top of step t (into buffer freed by the
// previous barrier), then ds_read+MFMA, then one vmcnt(0)+barrier per step.
__global__ __launch_bounds__(512, 2) void k_ffn1(const ushort* __restrict__ xb,
                                                 const ushort* __restrict__ wgb,
                                                 const ushort* __restrict__ wub,
                                                 const ushort* __restrict__ swgb,
                                                 const ushort* __restrict__ swub,
                                                 const int* __restrict__ meta,
                                                 const int* __restrict__ tok_sorted,
                                                 const float* __restrict__ w_sorted,
                                                 ushort* __restrict__ Hbuf,
                                                 const float* __restrict__ w_down,
                                                 const float* __restrict__ sw_down,
                                                 ushort* __restrict__ wdb,
                                                 ushort* __restrict__ swdb) {
    const int tid = threadIdx.x;
    if (blockIdx.x >= GEMMB1) {
        // fused cvt tail: wdb then swdb (needed only by ffn2)
        const int NW8 = NE * F_ * D_ / 8;
        const int NSW8 = F_ * D_ / 8;
        int ci = (blockIdx.x - GEMMB1) * 512 + tid;
        const int cstride = CVTB * 512;
        for (; ci < NW8 + NSW8; ci += cstride) {
            if (ci < NW8) cvt_store8(wdb + (size_t)ci * 8, w_down + (size_t)ci * 8);
            else {
                int j = ci - NW8;
                cvt_store8(swdb + (size_t)j * 8, sw_down + (size_t)j * 8);
            }
        }
        return;
    }

    int e, row0, fx;
    const int lbid = xcd_map(blockIdx.x, GEMMB1);
    if (!grid_decode(meta, lbid, NF1, e, row0, fx)) return;
    int n_e, base;
    if (e < NE) { n_e = meta[e]; base = meta[32 + e]; }
    else        { n_e = NTOK;    base = SHARED_BASE; }
    const int f0 = fx * BN1;
    const ushort* wg = (e < NE) ? wgb + (size_t)e * F_ * D_ : swgb;
    const ushort* wu = (e < NE) ? wub + (size_t)e * F_ * D_ : swub;

    __shared__ __align__(16) ushort As[2][BM1 * BK]; // 64 KB
    __shared__ __align__(16) ushort Gs[2][BN1 * BK]; // 32 KB
    __shared__ __align__(16) ushort Us[2][BN1 * BK]; // 32 KB
    __shared__ int tks[BM1];
    __shared__ float tws[BM1];

    const int wv = tid >> 6, lane = tid & 63;
    if (tid < BM1) {
        int r = row0 + tid;
        if (r < n_e) {
            tks[tid] = (e < NE) ? tok_sorted[base + r] : r;
            tws[tid] = (e < NE) ? w_sorted[base + r] : 1.0f;
        } else { tks[tid] = 0; tws[tid] = 0.f; }
    }
    __syncthreads();

    const ushort* srcA[4]; const ushort* srcG[2]; const ushort* srcU[2];
#pragma unroll
    for (int j = 0; j < 4; ++j) {
        int c = j * 512 + wv * 64 + lane;
        int r = c >> 3;
        int col = ((c & 7) ^ (r & 7)) * 8;
        srcA[j] = xb + (size_t)tks[r] * D_ + col;
    }
#pragma unroll
    for (int j = 0; j < 2; ++j) {
        int c = j * 512 + wv * 64 + lane;
        int r = c >> 3;
        int col = ((c & 7) ^ (r & 7)) * 8;
        srcG[j] = wg + (size_t)(f0 + r) * D_ + col;
        srcU[j] = wu + (size_t)(f0 + r) * D_ + col;
    }

    auto stage = [&](int buf, int k0) {
        char* bA = (char*)(&As[buf][0]) + wv * 1024;
        char* bG = (char*)(&Gs[buf][0]) + wv * 1024;
        char* bU = (char*)(&Us[buf][0]) + wv * 1024;
        gll16(srcA[0] + k0, bA);         gll16(srcA[1] + k0, bA + 8192);
        gll16(srcA[2] + k0, bA + 16384); gll16(srcA[3] + k0, bA + 24576);
        gll16(srcG[0] + k0, bG);         gll16(srcG[1] + k0, bG + 8192);
        gll16(srcU[0] + k0, bU);         gll16(srcU[1] + k0, bU + 8192);
    };

    f32x4 accg[4][4] = {}; f32x4 accu[4][4] = {};
    const int wm = (wv >> 1) * 64, wn = (wv & 1) * 64;
    const int fr = lane & 15, fq = lane >> 4;
    const int sw = fr & 7;
    const int rc0 = ((fq ^ sw) * 8);
    const int rc1 = (((4 + fq) ^ sw) * 8);

    auto compute = [&](int buf) {
        const ushort* pA = As[buf];
        const ushort* pG = Gs[buf];
        const ushort* pU = Us[buf];
#pragma unroll
        for (int kk = 0; kk < 2; ++kk) {
            const int rc = kk ? rc1 : rc0;
            short8 af[4], gf[4], uf[4];
#pragma unroll
            for (int mi = 0; mi < 4; ++mi)
                af[mi] = *reinterpret_cast<const short8*>(&pA[(wm + mi * 16 + fr) * BK + rc]);
#pragma unroll
            for (int ni = 0; ni < 4; ++ni) {
                gf[ni] = *reinterpret_cast<const short8*>(&pG[(wn + ni * 16 + fr) * BK + rc]);
                uf[ni] = *reinterpret_cast<const short8*>(&pU[(wn + ni * 16 + fr) * BK + rc]);
            }
#pragma unroll
            for (int mi = 0; mi < 4; ++mi)
#pragma unroll
                for (int ni = 0; ni < 4; ++ni) {
                    accg[mi][ni] = __builtin_amdgcn_mfma_f32_16x16x32_bf16(af[mi], gf[ni], accg[mi][ni], 0, 0, 0);
                    accu[mi][ni] = __builtin_amdgcn_mfma_f32_16x16x32_bf16(af[mi], uf[ni], accu[mi][ni], 0, 0, 0);
                }
        }
    };

    // T3 minimum-2-phase pipeline: one vmcnt(0)+barrier per K-step.
    const int NK = D_ / BK; // 32
    stage(0, 0);
    asm volatile("s_waitcnt vmcnt(0)" ::: "memory"); // tile 0 landed (own loads)
    __builtin_amdgcn_s_barrier();                    // everyone's tile 0 landed
    __builtin_amdgcn_sched_barrier(0);
    int cur = 0;
    for (int ks = 0; ks < NK; ++ks) {
        if (ks + 1 < NK) stage(cur ^ 1, (ks + 1) * BK); // issue FIRST (other buffer,
        __builtin_amdgcn_sched_barrier(0);              //  freed by prev barrier)
        compute(cur);                                   // ds_read+MFMA hide the flight
        if (ks + 1 < NK)
            asm volatile("s_waitcnt vmcnt(0)" ::: "memory"); // tile ks+1 landed
        __builtin_amdgcn_s_barrier();                   // reads done + staged visible
        __builtin_amdgcn_sched_barrier(0);
        cur ^= 1;
    }

    // epilogue: h = w * silu(g)*u -> Hbuf bf16 (pre-scaled by routing weight)
#pragma unroll
    for (int mi = 0; mi < 4; ++mi) {
#pragma unroll
        for (int r = 0; r < 4; ++r) {
            int lr = wm + mi * 16 + fq * 4 + r;
            int grow = row0 + lr;
            if (grow < n_e) {
                float w = tws[lr];
                ushort* hrow = Hbuf + (size_t)(base + grow) * F_ + f0 + wn;
#pragma unroll
                for (int ni = 0; ni < 4; ++ni) {
                    float g = accg[mi][ni][r];
                    float u = accu[mi][ni][r];
                    float h = w * (g / (1.f + __expf(-g))) * u;
                    hrow[ni * 16 + fr] = f2bf(h);
                }
            }
        }
    }
}

// ---------------- pass B: O[slot] = H[slot] @ wd^T ----------------
// 256x256 tile (acc[4][8]) + XCD map; T3-min loop (one vmcnt+barrier/step).
__global__ __launch_bounds__(512, 2) void k_ffn2(const ushort* __restrict__ Hbuf,
                                                 const ushort* __restrict__ wdb,
                                                 const ushort* __restrict__ swdb,
                                                 const int* __restrict__ meta,
                                                 ushort* __restrict__ Obuf) {
    int e, row0, dx;
    const int lbid = xcd_map(blockIdx.x, gridDim.x);
    if (!grid_decode(meta, lbid, NF2, e, row0, dx)) return;
    int n_e, base;
    if (e < NE) { n_e = meta[e]; base = meta[32 + e]; }
    else        { n_e = NTOK;    base = SHARED_BASE; }
    const int d0 = dx * BN2;
    const ushort* wd = (e < NE) ? wdb + (size_t)e * D_ * F_ : swdb;

    __shared__ __align__(16) ushort As[2][BM1 * BK]; // 64 KB
    __shared__ __align__(16) ushort Bs[2][BN2 * BK]; // 64 KB

    const int tid = threadIdx.x;
    const int wv = tid >> 6, lane = tid & 63;

    const ushort* srcA[4]; const ushort* srcB[4];
#pragma unroll
    for (int j = 0; j < 4; ++j) {
        int c = j * 512 + wv * 64 + lane;
        int r = c >> 3;
        int col = ((c & 7) ^ (r & 7)) * 8;
        srcA[j] = Hbuf + (size_t)(base + row0 + r) * F_ + col; // in-bounds of ws
        srcB[j] = wd + (size_t)(d0 + r) * F_ + col;
    }

    auto stage = [&](int buf, int k0) {
        char* bA = (char*)(&As[buf][0]) + wv * 1024;
        char* bB = (char*)(&Bs[buf][0]) + wv * 1024;
        gll16(srcA[0] + k0, bA);         gll16(srcA[1] + k0, bA + 8192);
        gll16(srcA[2] + k0, bA + 16384); gll16(srcA[3] + k0, bA + 24576);
        gll16(srcB[0] + k0, bB);         gll16(srcB[1] + k0, bB + 8192);
        gll16(srcB[2] + k0, bB + 16384); gll16(srcB[3] + k0, bB + 24576);
    };

    f32x4 acc[4][8] = {};
    const int wm = (wv >> 1) * 64, wn = (wv & 1) * 128;
    const int fr = lane & 15, fq = lane >> 4;
    const int sw = fr & 7;
    const int rc0 = ((fq ^ sw) * 8);
    const int rc1 = (((4 + fq) ^ sw) * 8);

    auto compute = [&](int buf) {
        const ushort* pA = As[buf];
        const ushort* pB = Bs[buf];
#pragma unroll
        for (int kk = 0; kk < 2; ++kk) {
            const int rc = kk ? rc1 : rc0;
            short8 af[4], bfr[8];
#pragma unroll
            for (int mi = 0; mi < 4; ++mi)
                af[mi] = *reinterpret_cast<const short8*>(&pA[(wm + mi * 16 + fr) * BK + rc]);
#pragma unroll
            for (int ni = 0; ni < 8; ++ni)
                bfr[ni] = *reinterpret_cast<const short8*>(&pB[(wn + ni * 16 + fr) * BK + rc]);
#pragma unroll
            for (int mi = 0; mi < 4; ++mi)
#pragma unroll
                for (int ni = 0; ni < 8; ++ni)
                    acc[mi][ni] = __builtin_amdgcn_mfma_f32_16x16x32_bf16(af[mi], bfr[ni], acc[mi][ni], 0, 0, 0);
        }
    };

    const int NK = F_ / BK; // 22
    stage(0, 0);
    asm volatile("s_waitcnt vmcnt(0)" ::: "memory");
    __builtin_amdgcn_s_barrier();
    __builtin_amdgcn_sched_barrier(0);
    int cur = 0;
    for (int ks = 0; ks < NK; ++ks) {
        if (ks + 1 < NK) stage(cur ^ 1, (ks + 1) * BK);
        __builtin_amdgcn_sched_barrier(0);
        compute(cur);
        if (ks + 1 < NK)
            asm volatile("s_waitcnt vmcnt(0)" ::: "memory");
        __builtin_amdgcn_s_barrier();
        __builtin_amdgcn_sched_barrier(0);
        cur ^= 1;
    }

    // epilogue: plain coalesced bf16 stores to the slot-row of O
#pragma unroll
    for (int mi = 0; mi < 4; ++mi) {
#pragma unroll
        for (int r = 0; r < 4; ++r) {
            int lr = wm + mi * 16 + fq * 4 + r;
            int slot = row0 + lr;
            if (slot < n_e) {
                ushort* orow = Obuf + (size_t)(base + slot) * D_ + d0 + wn;
#pragma unroll
                for (int ni = 0; ni < 8; ++ni)
                    orow[ni * 16 + fr] = f2bf(acc[mi][ni][r]);
            }
        }
    }
}

// ---------------- gather: out[t] = O[slot1] + O[slot2] + O[shared+t] ----------------
__global__ __launch_bounds__(256) void k_gather(const ushort* __restrict__ Obuf,
                                                const int* __restrict__ inv,
                                                float* __restrict__ out) {
    const int t = blockIdx.x;
    const int c = threadIdx.x * 8;
    const int s1 = inv[t * 2 + 0];
    const int s2 = inv[t * 2 + 1];
    short8 a = *reinterpret_cast<const short8*>(&Obuf[(size_t)s1 * D_ + c]);
    short8 b = *reinterpret_cast<const short8*>(&Obuf[(size_t)s2 * D_ + c]);
    short8 d = *reinterpret_cast<const short8*>(&Obuf[(size_t)(SHARED_BASE + t) * D_ + c]);
    float4 o0, o1;
    o0.x = bf2f((ushort)a[0]) + bf2f((ushort)b[0]) + bf2f((ushort)d[0]);
    o0.y = bf2f((ushort)a[1]) + bf2f((ushort)b[1]) + bf2f((ushort)d[1]);
    o0.z = bf2f((ushort)a[2]) + bf2f((ushort)b[2]) + bf2f((ushort)d[2]);
    o0.w = bf2f((ushort)a[3]) + bf2f((ushort)b[3]) + bf2f((ushort)d[3]);
    o1.x = bf2f((ushort)a[4]) + bf2f((ushort)b[4]) + bf2f((ushort)d[4]);
    o1.y = bf2f((ushort)a[5]) + bf2f((ushort)b[5]) + bf2f((ushort)d[5]);
    o1.z = bf2f((ushort)a[6]) + bf2f((ushort)b[6]) + bf2f((ushort)d[6]);
    o1.w = bf2f((ushort)a[7]) + bf2f((ushort)b[7]) + bf2f((ushort)d[7]);
    float4* op = reinterpret_cast<float4*>(out + (size_t)t * D_ + c);
    op[0] = o0; op[1] = o1;
}

extern "C" void kernel_launch(void* const* d_in, const int* in_sizes, int n_in,
                              void* d_out, int out_size, void* d_ws, size_t ws_size,
                              hipStream_t stream) {
    const float* x        = (const float*)d_in[0];
    const float* gate_w   = (const float*)d_in[1];
    const float* w_gate   = (const float*)d_in[2];
    const float* w_up     = (const float*)d_in[3];
    const float* w_down   = (const float*)d_in[4];
    const float* sw_gate  = (const float*)d_in[5];
    const float* sw_up    = (const float*)d_in[6];
    const float* sw_down  = (const float*)d_in[7];
    const float* expert_bias = (const float*)d_in[8];
    float* out = (float*)d_out;

    const size_t NW = (size_t)NE * F_ * D_;
    const size_t NSW = (size_t)F_ * D_;
    const size_t NX = (size_t)NTOK * D_;

    char* ws = (char*)d_ws;
    size_t off = 0;
    ushort* xb   = (ushort*)(ws + off); off += NX * 2;
    ushort* wgb  = (ushort*)(ws + off); off += NW * 2;
    ushort* wub  = (ushort*)(ws + off); off += NW * 2;
    ushort* wdb  = (ushort*)(ws + off); off += NW * 2;
    ushort* swgb = (ushort*)(ws + off); off += NSW * 2;
    ushort* swub = (ushort*)(ws + off); off += NSW * 2;
    ushort* swdb = (ushort*)(ws + off); off += NSW * 2;
    ushort* Hbuf = (ushort*)(ws + off); off += (size_t)NTOT * F_ * 2;
    int* tok_sorted = (int*)(ws + off); off += NPAIR * sizeof(int);
    float* w_sorted = (float*)(ws + off); off += NPAIR * sizeof(float);
    int* topk_idx = (int*)(ws + off); off += NTOK * 2 * sizeof(int);
    float* topk_w = (float*)(ws + off); off += NTOK * 2 * sizeof(float);
    int* inv = (int*)(ws + off); off += NTOK * 2 * sizeof(int);
    int* meta = (int*)(ws + off); off += 512;

    // O buffer (NTOT x D_ bf16, 100.7 MB) aliases wgb+wub (dead after k_ffn1)
    ushort* Obuf = wgb;

    // routing + fused cvt of all ffn1 inputs (one dispatch replaces 6)
    k_route<<<ROUTEB + CVTB2, 256, 0, stream>>>(x, gate_w, expert_bias, topk_idx, topk_w,
                                                w_gate, w_up, sw_gate, sw_up,
                                                xb, wgb, wub, swgb, swub);
    k_zero_meta<<<1, 128, 0, stream>>>(meta);
    k_count<<<NTOK / 256, 256, 0, stream>>>(topk_idx, meta);
    k_prefix<<<1, 1, 0, stream>>>(meta);
    k_scatter<<<NTOK / 256, 256, 0, stream>>>(topk_idx, topk_w, meta, tok_sorted, w_sorted, inv);

    // compact 1D expert-major, fx-major-within-expert grid + fused cvt tail
    k_ffn1<<<GEMMB1 + CVTB, 512, 0, stream>>>(xb, wgb, wub, swgb, swub,
                                              meta, tok_sorted, w_sorted, Hbuf,
                                              w_down, sw_down, wdb, swdb);

    k_ffn2<<<MAXRT * NF2, 512, 0, stream>>>(Hbuf, wdb, swdb, meta, Obuf);

    k_gather<<<NTOK, 256, 0, stream>>>(Obuf, inv, out);
}

// Round 20
// 871.918 us; speedup vs baseline: 1.0410x; 1.0410x over previous
//
#include <hip/hip_runtime.h>
#include <hip/hip_bf16.h>
#include <cstdint>

// Problem constants
#define NE 16            // experts
#define D_ 2048          // d_model
#define F_ 1408          // ffn hidden
#define NTOK 8192        // B*S
#define NPAIR (NTOK * 2) // routed token-expert pairs
#define SHARED_BASE NPAIR
#define NTOT (NPAIR + NTOK) // + shared-expert rows

// ffn1: BM=256 x BN=128, BK=64, 8 waves, counted-vmcnt 2-deep pipeline
//       (R15 form) + cvt tail for w_down/sw_down (R17, proven −22us).
// ffn2: BM=256 x BN=256, BK=64, 8 waves (R15 form) + XCD-chunked block map.
// route: routing blocks + cvt tail for x/wg/wu/swg/swu (replaces 5 launches).
// R19's stage-first/1-deep reorder REGRESSED (908us) — this is the R18 loop.
#define BM1 256
#define BN1 128
#define BN2 256
#define BK 64
#define NF1 (F_ / BN1)   // 11 f-tiles in ffn1
#define NF2 (D_ / BN2)   // 8 d-tiles in ffn2
#define MAXRT 111        // worst-case row-tiles: 79 routed + 32 shared
#define GEMMB1 (MAXRT * NF1) // 1221 GEMM blocks in ffn1
#define CVTB 512             // cvt tail blocks fused into ffn1
#define ROUTEB (NTOK / 4)    // 2048 routing blocks
#define CVTB2 2048           // cvt tail blocks fused into route

typedef __attribute__((ext_vector_type(8))) short short8;
typedef __attribute__((ext_vector_type(4))) float f32x4;

static __device__ __forceinline__ ushort f2bf(float f) {
    union { float f; unsigned u; } v; v.f = f;
    unsigned u = v.u;
    return (ushort)((u + 0x7FFFu + ((u >> 16) & 1u)) >> 16); // RNE
}

static __device__ __forceinline__ float bf2f(ushort u) {
    union { unsigned u; float f; } v; v.u = ((unsigned)u) << 16;
    return v.f;
}

static __device__ __forceinline__ void cvt_store8(ushort* dst, const float* src) {
    const float4* s = reinterpret_cast<const float4*>(src);
    float4 a = s[0], b = s[1];
    short8 v;
    v[0] = (short)f2bf(a.x); v[1] = (short)f2bf(a.y);
    v[2] = (short)f2bf(a.z); v[3] = (short)f2bf(a.w);
    v[4] = (short)f2bf(b.x); v[5] = (short)f2bf(b.y);
    v[6] = (short)f2bf(b.z); v[7] = (short)f2bf(b.w);
    *reinterpret_cast<short8*>(dst) = v;
}

// async global->LDS, 16B/lane; LDS dest = wave-uniform base (+lane*16 implicit)
static __device__ __forceinline__ void gll16(const void* g, void* l) {
    __builtin_amdgcn_global_load_lds((const __attribute__((address_space(1))) void*)g,
                                     (__attribute__((address_space(3))) void*)l, 16, 0, 0);
}

// T1: bijective XCD-chunking (m204). Physical block p -> XCD p%8; this gives
// each XCD a contiguous logical range so fx/dx-major neighbors (same weight
// panel) share one per-XCD L2. Proven on ffn1 (FETCH 7.0e5 -> 3.8e5 KB).
static __device__ __forceinline__ int xcd_map(int p, int nwg) {
    int q = nwg >> 3, r = nwg & 7;
    int x = p & 7, k = p >> 3;
    int base = (x < r) ? x * (q + 1) : r * (q + 1) + (x - r) * q;
    return base + k;
}

// ---------------- routing (+ fused cvt tail for ffn1's inputs) ----------------
__global__ __launch_bounds__(256) void k_route(const float* __restrict__ x,
                                               const float* __restrict__ gate_w,
                                               const float* __restrict__ expert_bias,
                                               int* __restrict__ topk_idx,
                                               float* __restrict__ topk_w,
                                               const float* __restrict__ w_gate,
                                               const float* __restrict__ w_up,
                                               const float* __restrict__ sw_gate,
                                               const float* __restrict__ sw_up,
                                               ushort* __restrict__ xb,
                                               ushort* __restrict__ wgb,
                                               ushort* __restrict__ wub,
                                               ushort* __restrict__ swgb,
                                               ushort* __restrict__ swub) {
    if (blockIdx.x >= ROUTEB) {
        // fused cvt tail: x, w_gate, w_up, sw_gate, sw_up (16B chunks, grid-stride)
        const int NX8 = NTOK * D_ / 8;      // 2,097,152
        const int NW8 = NE * F_ * D_ / 8;   // 5,767,168
        const int NSW8 = F_ * D_ / 8;       // 360,448
        const int TOT = NX8 + 2 * NW8 + 2 * NSW8;
        int ci = (blockIdx.x - ROUTEB) * 256 + threadIdx.x;
        const int cstride = CVTB2 * 256;
        for (; ci < TOT; ci += cstride) {
            int j = ci;
            if (j < NX8) { cvt_store8(xb + (size_t)j * 8, x + (size_t)j * 8); continue; }
            j -= NX8;
            if (j < NW8) { cvt_store8(wgb + (size_t)j * 8, w_gate + (size_t)j * 8); continue; }
            j -= NW8;
            if (j < NW8) { cvt_store8(wub + (size_t)j * 8, w_up + (size_t)j * 8); continue; }
            j -= NW8;
            if (j < NSW8) { cvt_store8(swgb + (size_t)j * 8, sw_gate + (size_t)j * 8); continue; }
            j -= NSW8;
            cvt_store8(swub + (size_t)j * 8, sw_up + (size_t)j * 8);
        }
        return;
    }

    const int wave = threadIdx.x >> 6;
    const int lane = threadIdx.x & 63;
    const int tok = blockIdx.x * 4 + wave;
    if (tok >= NTOK) return;
    const float* xr = x + (size_t)tok * D_;
    float xv[D_ / 64];
#pragma unroll
    for (int i = 0; i < D_ / 64; ++i) xv[i] = xr[lane + 64 * i];

    float logits[NE];
#pragma unroll
    for (int e = 0; e < NE; ++e) {
        const float* gw = gate_w + e * D_;
        float p = 0.f;
#pragma unroll
        for (int i = 0; i < D_ / 64; ++i) p += xv[i] * gw[lane + 64 * i];
#pragma unroll
        for (int off = 32; off > 0; off >>= 1) p += __shfl_xor(p, off, 64);
        logits[e] = p;
    }
    int i1 = 0; float b1 = logits[0] + expert_bias[0];
#pragma unroll
    for (int e = 1; e < NE; ++e) {
        float b = logits[e] + expert_bias[e];
        if (b > b1) { b1 = b; i1 = e; }
    }
    int i2 = -1; float b2 = -3.4e38f;
#pragma unroll
    for (int e = 0; e < NE; ++e) {
        if (e == i1) continue;
        float b = logits[e] + expert_bias[e];
        if (b > b2) { b2 = b; i2 = e; }
    }
    float l1 = logits[i1], l2 = logits[i2];
    float m = fmaxf(l1, l2);
    float e1 = __expf(l1 - m), e2 = __expf(l2 - m);
    float s = e1 + e2;
    if (lane == 0) {
        topk_idx[tok * 2 + 0] = i1;
        topk_idx[tok * 2 + 1] = i2;
        topk_w[tok * 2 + 0] = e1 / s;
        topk_w[tok * 2 + 1] = e2 / s;
    }
}

// ---------------- bookkeeping ----------------
// meta (ints): [0:16) cnt, [16:32) cnt2, [32:49) row prefix,
//              [64:82) block-tile prefix (16 experts, then routed total, then +shared)
__global__ void k_zero_meta(int* meta) {
    if (threadIdx.x < 128) meta[threadIdx.x] = 0;
}

__global__ __launch_bounds__(256) void k_count(const int* __restrict__ topk_idx,
                                               int* __restrict__ meta) {
    int t = blockIdx.x * 256 + threadIdx.x;
    if (t >= NTOK) return;
    atomicAdd(&meta[topk_idx[t * 2 + 0]], 1);
    atomicAdd(&meta[topk_idx[t * 2 + 1]], 1);
}

__global__ void k_prefix(int* meta) {
    if (threadIdx.x == 0) {
        int acc = 0;
        for (int e = 0; e < NE; ++e) { meta[32 + e] = acc; acc += meta[e]; }
        meta[32 + NE] = acc;
        int t = 0;
        for (int e = 0; e < NE; ++e) { meta[64 + e] = t; t += (meta[e] + BM1 - 1) / BM1; }
        meta[64 + NE] = t;                  // routed tile total == start of shared tiles
        meta[64 + NE + 1] = t + NTOK / BM1; // total incl shared
    }
}

__global__ __launch_bounds__(256) void k_scatter(const int* __restrict__ topk_idx,
                                                 const float* __restrict__ topk_w,
                                                 int* __restrict__ meta,
                                                 int* __restrict__ tok_sorted,
                                                 float* __restrict__ w_sorted,
                                                 int* __restrict__ inv) {
    int t = blockIdx.x * 256 + threadIdx.x;
    if (t >= NTOK) return;
#pragma unroll
    for (int k = 0; k < 2; ++k) {
        int e = topk_idx[t * 2 + k];
        int p = atomicAdd(&meta[16 + e], 1);
        int idx = meta[32 + e] + p;
        tok_sorted[idx] = t;
        w_sorted[idx] = topk_w[t * 2 + k];
        inv[t * 2 + k] = idx; // token -> slot map for the gather
    }
}

// expert lookup for fx-major compact grids
static __device__ __forceinline__ bool grid_decode(const int* meta, int bid, int NF,
                                                   int& e, int& row0, int& fx) {
    if (bid >= meta[64 + NE + 1] * NF) return false;
    e = (bid >= meta[64 + NE] * NF) ? NE : 0;
    if (e == 0) {
#pragma unroll
        for (int i = 1; i < NE; ++i) if (bid >= meta[64 + i] * NF) e = i;
    }
    const int tile_base = meta[64 + e];
    const int nrt = meta[64 + e + 1] - tile_base;
    const int bw = bid - tile_base * NF;
    fx = bw / nrt;
    row0 = (bw - fx * nrt) * BM1;
    return true;
}

// ---------------- pass A: h = w_route * silu(x@wg^T) * (x@wu^T) ----------------
// R15 form + cvt tail (w_down/sw_down) during the GEMM's ragged dispatch tail.
__global__ __launch_bounds__(512, 2) void k_ffn1(const ushort* __restrict__ xb,
                                                 const ushort* __restrict__ wgb,
                                                 const ushort* __restrict__ wub,
                                                 const ushort* __restrict__ swgb,
                                                 const ushort* __restrict__ swub,
                                                 const int* __restrict__ meta,
                                                 const int* __restrict__ tok_sorted,
                                                 const float* __restrict__ w_sorted,
                                                 ushort* __restrict__ Hbuf,
                                                 const float* __restrict__ w_down,
                                                 const float* __restrict__ sw_down,
                                                 ushort* __restrict__ wdb,
                                                 ushort* __restrict__ swdb) {
    const int tid = threadIdx.x;
    if (blockIdx.x >= GEMMB1) {
        // fused cvt tail: wdb then swdb (needed only by ffn2)
        const int NW8 = NE * F_ * D_ / 8;
        const int NSW8 = F_ * D_ / 8;
        int ci = (blockIdx.x - GEMMB1) * 512 + tid;
        const int cstride = CVTB * 512;
        for (; ci < NW8 + NSW8; ci += cstride) {
            if (ci < NW8) cvt_store8(wdb + (size_t)ci * 8, w_down + (size_t)ci * 8);
            else {
                int j = ci - NW8;
                cvt_store8(swdb + (size_t)j * 8, sw_down + (size_t)j * 8);
            }
        }
        return;
    }

    int e, row0, fx;
    const int lbid = xcd_map(blockIdx.x, GEMMB1);
    if (!grid_decode(meta, lbid, NF1, e, row0, fx)) return;
    int n_e, base;
    if (e < NE) { n_e = meta[e]; base = meta[32 + e]; }
    else        { n_e = NTOK;    base = SHARED_BASE; }
    const int f0 = fx * BN1;
    const ushort* wg = (e < NE) ? wgb + (size_t)e * F_ * D_ : swgb;
    const ushort* wu = (e < NE) ? wub + (size_t)e * F_ * D_ : swub;

    __shared__ __align__(16) ushort As[2][BM1 * BK]; // 64 KB
    __shared__ __align__(16) ushort Gs[2][BN1 * BK]; // 32 KB
    __shared__ __align__(16) ushort Us[2][BN1 * BK]; // 32 KB
    __shared__ int tks[BM1];
    __shared__ float tws[BM1];

    const int wv = tid >> 6, lane = tid & 63;
    if (tid < BM1) {
        int r = row0 + tid;
        if (r < n_e) {
            tks[tid] = (e < NE) ? tok_sorted[base + r] : r;
            tws[tid] = (e < NE) ? w_sorted[base + r] : 1.0f;
        } else { tks[tid] = 0; tws[tid] = 0.f; }
    }
    __syncthreads();

    const ushort* srcA[4]; const ushort* srcG[2]; const ushort* srcU[2];
#pragma unroll
    for (int j = 0; j < 4; ++j) {
        int c = j * 512 + wv * 64 + lane;
        int r = c >> 3;
        int col = ((c & 7) ^ (r & 7)) * 8;
        srcA[j] = xb + (size_t)tks[r] * D_ + col;
    }
#pragma unroll
    for (int j = 0; j < 2; ++j) {
        int c = j * 512 + wv * 64 + lane;
        int r = c >> 3;
        int col = ((c & 7) ^ (r & 7)) * 8;
        srcG[j] = wg + (size_t)(f0 + r) * D_ + col;
        srcU[j] = wu + (size_t)(f0 + r) * D_ + col;
    }

    auto stage = [&](int buf, int k0) {
        char* bA = (char*)(&As[buf][0]) + wv * 1024;
        char* bG = (char*)(&Gs[buf][0]) + wv * 1024;
        char* bU = (char*)(&Us[buf][0]) + wv * 1024;
        gll16(srcA[0] + k0, bA);         gll16(srcA[1] + k0, bA + 8192);
        gll16(srcA[2] + k0, bA + 16384); gll16(srcA[3] + k0, bA + 24576);
        gll16(srcG[0] + k0, bG);         gll16(srcG[1] + k0, bG + 8192);
        gll16(srcU[0] + k0, bU);         gll16(srcU[1] + k0, bU + 8192);
    };

    f32x4 accg[4][4] = {}; f32x4 accu[4][4] = {};
    const int wm = (wv >> 1) * 64, wn = (wv & 1) * 64;
    const int fr = lane & 15, fq = lane >> 4;
    const int sw = fr & 7;
    const int rc0 = ((fq ^ sw) * 8);
    const int rc1 = (((4 + fq) ^ sw) * 8);

    auto compute = [&](int buf) {
        const ushort* pA = As[buf];
        const ushort* pG = Gs[buf];
        const ushort* pU = Us[buf];
#pragma unroll
        for (int kk = 0; kk < 2; ++kk) {
            const int rc = kk ? rc1 : rc0;
            short8 af[4], gf[4], uf[4];
#pragma unroll
            for (int mi = 0; mi < 4; ++mi)
                af[mi] = *reinterpret_cast<const short8*>(&pA[(wm + mi * 16 + fr) * BK + rc]);
#pragma unroll
            for (int ni = 0; ni < 4; ++ni) {
                gf[ni] = *reinterpret_cast<const short8*>(&pG[(wn + ni * 16 + fr) * BK + rc]);
                uf[ni] = *reinterpret_cast<const short8*>(&pU[(wn + ni * 16 + fr) * BK + rc]);
            }
#pragma unroll
            for (int mi = 0; mi < 4; ++mi)
#pragma unroll
                for (int ni = 0; ni < 4; ++ni) {
                    accg[mi][ni] = __builtin_amdgcn_mfma_f32_16x16x32_bf16(af[mi], gf[ni], accg[mi][ni], 0, 0, 0);
                    accu[mi][ni] = __builtin_amdgcn_mfma_f32_16x16x32_bf16(af[mi], uf[ni], accu[mi][ni], 0, 0, 0);
                }
        }
    };

    // counted-vmcnt 2-deep pipeline (T4)
    const int NK = D_ / BK; // 32
    stage(0, 0);
    stage(1, BK);
    asm volatile("s_waitcnt vmcnt(8)" ::: "memory"); // tile 0 landed
    __builtin_amdgcn_s_barrier();
    __builtin_amdgcn_sched_barrier(0);
    int cur = 0;
    for (int ks = 0; ks < NK; ++ks) {
        compute(cur);
        __builtin_amdgcn_s_barrier();                // all waves done reading buf cur
        if (ks + 2 < NK) {
            stage(cur, (ks + 2) * BK);               // overwrite cur with tile ks+2
            asm volatile("s_waitcnt vmcnt(8)" ::: "memory"); // tile ks+1 landed
        } else if (ks + 1 < NK) {
            asm volatile("s_waitcnt vmcnt(0)" ::: "memory"); // tail drain
        }
        __builtin_amdgcn_s_barrier();
        __builtin_amdgcn_sched_barrier(0);
        cur ^= 1;
    }

    // epilogue: h = w * silu(g)*u -> Hbuf bf16 (pre-scaled by routing weight)
#pragma unroll
    for (int mi = 0; mi < 4; ++mi) {
#pragma unroll
        for (int r = 0; r < 4; ++r) {
            int lr = wm + mi * 16 + fq * 4 + r;
            int grow = row0 + lr;
            if (grow < n_e) {
                float w = tws[lr];
                ushort* hrow = Hbuf + (size_t)(base + grow) * F_ + f0 + wn;
#pragma unroll
                for (int ni = 0; ni < 4; ++ni) {
                    float g = accg[mi][ni][r];
                    float u = accu[mi][ni][r];
                    float h = w * (g / (1.f + __expf(-g))) * u;
                    hrow[ni * 16 + fr] = f2bf(h);
                }
            }
        }
    }
}

// ---------------- pass B: O[slot] = H[slot] @ wd^T ----------------
// 256x256 tile (acc[4][8]), vmcnt(8) (R15 form) + XCD-chunked block map.
__global__ __launch_bounds__(512, 2) void k_ffn2(const ushort* __restrict__ Hbuf,
                                                 const ushort* __restrict__ wdb,
                                                 const ushort* __restrict__ swdb,
                                                 const int* __restrict__ meta,
                                                 ushort* __restrict__ Obuf) {
    int e, row0, dx;
    const int lbid = xcd_map(blockIdx.x, gridDim.x);
    if (!grid_decode(meta, lbid, NF2, e, row0, dx)) return;
    int n_e, base;
    if (e < NE) { n_e = meta[e]; base = meta[32 + e]; }
    else        { n_e = NTOK;    base = SHARED_BASE; }
    const int d0 = dx * BN2;
    const ushort* wd = (e < NE) ? wdb + (size_t)e * D_ * F_ : swdb;

    __shared__ __align__(16) ushort As[2][BM1 * BK]; // 64 KB
    __shared__ __align__(16) ushort Bs[2][BN2 * BK]; // 64 KB

    const int tid = threadIdx.x;
    const int wv = tid >> 6, lane = tid & 63;

    const ushort* srcA[4]; const ushort* srcB[4];
#pragma unroll
    for (int j = 0; j < 4; ++j) {
        int c = j * 512 + wv * 64 + lane;
        int r = c >> 3;
        int col = ((c & 7) ^ (r & 7)) * 8;
        srcA[j] = Hbuf + (size_t)(base + row0 + r) * F_ + col; // in-bounds of ws
        srcB[j] = wd + (size_t)(d0 + r) * F_ + col;
    }

    auto stage = [&](int buf, int k0) {
        char* bA = (char*)(&As[buf][0]) + wv * 1024;
        char* bB = (char*)(&Bs[buf][0]) + wv * 1024;
        gll16(srcA[0] + k0, bA);         gll16(srcA[1] + k0, bA + 8192);
        gll16(srcA[2] + k0, bA + 16384); gll16(srcA[3] + k0, bA + 24576);
        gll16(srcB[0] + k0, bB);         gll16(srcB[1] + k0, bB + 8192);
        gll16(srcB[2] + k0, bB + 16384); gll16(srcB[3] + k0, bB + 24576);
    };

    f32x4 acc[4][8] = {};
    const int wm = (wv >> 1) * 64, wn = (wv & 1) * 128;
    const int fr = lane & 15, fq = lane >> 4;
    const int sw = fr & 7;
    const int rc0 = ((fq ^ sw) * 8);
    const int rc1 = (((4 + fq) ^ sw) * 8);

    auto compute = [&](int buf) {
        const ushort* pA = As[buf];
        const ushort* pB = Bs[buf];
#pragma unroll
        for (int kk = 0; kk < 2; ++kk) {
            const int rc = kk ? rc1 : rc0;
            short8 af[4], bfr[8];
#pragma unroll
            for (int mi = 0; mi < 4; ++mi)
                af[mi] = *reinterpret_cast<const short8*>(&pA[(wm + mi * 16 + fr) * BK + rc]);
#pragma unroll
            for (int ni = 0; ni < 8; ++ni)
                bfr[ni] = *reinterpret_cast<const short8*>(&pB[(wn + ni * 16 + fr) * BK + rc]);
#pragma unroll
            for (int mi = 0; mi < 4; ++mi)
#pragma unroll
                for (int ni = 0; ni < 8; ++ni)
                    acc[mi][ni] = __builtin_amdgcn_mfma_f32_16x16x32_bf16(af[mi], bfr[ni], acc[mi][ni], 0, 0, 0);
        }
    };

    const int NK = F_ / BK; // 22
    stage(0, 0);
    stage(1, BK);
    asm volatile("s_waitcnt vmcnt(8)" ::: "memory");
    __builtin_amdgcn_s_barrier();
    __builtin_amdgcn_sched_barrier(0);
    int cur = 0;
    for (int ks = 0; ks < NK; ++ks) {
        compute(cur);
        __builtin_amdgcn_s_barrier();
        if (ks + 2 < NK) {
            stage(cur, (ks + 2) * BK);
            asm volatile("s_waitcnt vmcnt(8)" ::: "memory");
        } else if (ks + 1 < NK) {
            asm volatile("s_waitcnt vmcnt(0)" ::: "memory");
        }
        __builtin_amdgcn_s_barrier();
        __builtin_amdgcn_sched_barrier(0);
        cur ^= 1;
    }

    // epilogue: plain coalesced bf16 stores to the slot-row of O
#pragma unroll
    for (int mi = 0; mi < 4; ++mi) {
#pragma unroll
        for (int r = 0; r < 4; ++r) {
            int lr = wm + mi * 16 + fq * 4 + r;
            int slot = row0 + lr;
            if (slot < n_e) {
                ushort* orow = Obuf + (size_t)(base + slot) * D_ + d0 + wn;
#pragma unroll
                for (int ni = 0; ni < 8; ++ni)
                    orow[ni * 16 + fr] = f2bf(acc[mi][ni][r]);
            }
        }
    }
}

// ---------------- gather: out[t] = O[slot1] + O[slot2] + O[shared+t] ----------------
__global__ __launch_bounds__(256) void k_gather(const ushort* __restrict__ Obuf,
                                                const int* __restrict__ inv,
                                                float* __restrict__ out) {
    const int t = blockIdx.x;
    const int c = threadIdx.x * 8;
    const int s1 = inv[t * 2 + 0];
    const int s2 = inv[t * 2 + 1];
    short8 a = *reinterpret_cast<const short8*>(&Obuf[(size_t)s1 * D_ + c]);
    short8 b = *reinterpret_cast<const short8*>(&Obuf[(size_t)s2 * D_ + c]);
    short8 d = *reinterpret_cast<const short8*>(&Obuf[(size_t)(SHARED_BASE + t) * D_ + c]);
    float4 o0, o1;
    o0.x = bf2f((ushort)a[0]) + bf2f((ushort)b[0]) + bf2f((ushort)d[0]);
    o0.y = bf2f((ushort)a[1]) + bf2f((ushort)b[1]) + bf2f((ushort)d[1]);
    o0.z = bf2f((ushort)a[2]) + bf2f((ushort)b[2]) + bf2f((ushort)d[2]);
    o0.w = bf2f((ushort)a[3]) + bf2f((ushort)b[3]) + bf2f((ushort)d[3]);
    o1.x = bf2f((ushort)a[4]) + bf2f((ushort)b[4]) + bf2f((ushort)d[4]);
    o1.y = bf2f((ushort)a[5]) + bf2f((ushort)b[5]) + bf2f((ushort)d[5]);
    o1.z = bf2f((ushort)a[6]) + bf2f((ushort)b[6]) + bf2f((ushort)d[6]);
    o1.w = bf2f((ushort)a[7]) + bf2f((ushort)b[7]) + bf2f((ushort)d[7]);
    float4* op = reinterpret_cast<float4*>(out + (size_t)t * D_ + c);
    op[0] = o0; op[1] = o1;
}

extern "C" void kernel_launch(void* const* d_in, const int* in_sizes, int n_in,
                              void* d_out, int out_size, void* d_ws, size_t ws_size,
                              hipStream_t stream) {
    const float* x        = (const float*)d_in[0];
    const float* gate_w   = (const float*)d_in[1];
    const float* w_gate   = (const float*)d_in[2];
    const float* w_up     = (const float*)d_in[3];
    const float* w_down   = (const float*)d_in[4];
    const float* sw_gate  = (const float*)d_in[5];
    const float* sw_up    = (const float*)d_in[6];
    const float* sw_down  = (const float*)d_in[7];
    const float* expert_bias = (const float*)d_in[8];
    float* out = (float*)d_out;

    const size_t NW = (size_t)NE * F_ * D_;
    const size_t NSW = (size_t)F_ * D_;
    const size_t NX = (size_t)NTOK * D_;

    char* ws = (char*)d_ws;
    size_t off = 0;
    ushort* xb   = (ushort*)(ws + off); off += NX * 2;
    ushort* wgb  = (ushort*)(ws + off); off += NW * 2;
    ushort* wub  = (ushort*)(ws + off); off += NW * 2;
    ushort* wdb  = (ushort*)(ws + off); off += NW * 2;
    ushort* swgb = (ushort*)(ws + off); off += NSW * 2;
    ushort* swub = (ushort*)(ws + off); off += NSW * 2;
    ushort* swdb = (ushort*)(ws + off); off += NSW * 2;
    ushort* Hbuf = (ushort*)(ws + off); off += (size_t)NTOT * F_ * 2;
    int* tok_sorted = (int*)(ws + off); off += NPAIR * sizeof(int);
    float* w_sorted = (float*)(ws + off); off += NPAIR * sizeof(float);
    int* topk_idx = (int*)(ws + off); off += NTOK * 2 * sizeof(int);
    float* topk_w = (float*)(ws + off); off += NTOK * 2 * sizeof(float);
    int* inv = (int*)(ws + off); off += NTOK * 2 * sizeof(int);
    int* meta = (int*)(ws + off); off += 512;

    // O buffer (NTOT x D_ bf16, 100.7 MB) aliases wgb+wub (dead after k_ffn1)
    ushort* Obuf = wgb;

    // routing + fused cvt of all ffn1 inputs (one dispatch replaces 6)
    k_route<<<ROUTEB + CVTB2, 256, 0, stream>>>(x, gate_w, expert_bias, topk_idx, topk_w,
                                                w_gate, w_up, sw_gate, sw_up,
                                                xb, wgb, wub, swgb, swub);
    k_zero_meta<<<1, 128, 0, stream>>>(meta);
    k_count<<<NTOK / 256, 256, 0, stream>>>(topk_idx, meta);
    k_prefix<<<1, 1, 0, stream>>>(meta);
    k_scatter<<<NTOK / 256, 256, 0, stream>>>(topk_idx, topk_w, meta, tok_sorted, w_sorted, inv);

    // compact 1D expert-major, fx-major-within-expert grid + fused cvt tail
    k_ffn1<<<GEMMB1 + CVTB, 512, 0, stream>>>(xb, wgb, wub, swgb, swub,
                                              meta, tok_sorted, w_sorted, Hbuf,
                                              w_down, sw_down, wdb, swdb);

    k_ffn2<<<MAXRT * NF2, 512, 0, stream>>>(Hbuf, wdb, swdb, meta, Obuf);

    k_gather<<<NTOK, 256, 0, stream>>>(Obuf, inv, out);
}